// Round 12
// baseline (203.155 us; speedup 1.0000x reference)
//
#include <hip/hip_runtime.h>
#include <hip/hip_fp16.h>
#include <math.h>

#define NN 100000
#define DEG 16
#define F_IN 128
#define F_OUT 32
#define NH 4
#define FTOT 128  // NH * F_OUT

typedef _Float16 f16x8 __attribute__((ext_vector_type(8)));
typedef float f32x4 __attribute__((ext_vector_type(4)));

// ---------------------------------------------------------------------------
// Kernel 0: one-time W fp32 -> fp16 convert (row-major [feat][k], linear).
// 2048 threads, one 8-half granule each.
// ---------------------------------------------------------------------------
__global__ __launch_bounds__(256) void k0_wprep(
    const float* __restrict__ W,    // [128][128]
    __half* __restrict__ W16) {     // [128][128] fp16
    const int g = blockIdx.x * 256 + threadIdx.x;  // 0..2047
    const int row = g >> 4;
    const int col = (g & 15) * 8;
    const float4 v0 = *(const float4*)(W + row * F_IN + col);
    const float4 v1 = *(const float4*)(W + row * F_IN + col + 4);
    union { __half2 h2[4]; float4 f; } u;
    u.h2[0] = __float22half2_rn(make_float2(v0.x, v0.y));
    u.h2[1] = __float22half2_rn(make_float2(v0.z, v0.w));
    u.h2[2] = __float22half2_rn(make_float2(v1.x, v1.y));
    u.h2[3] = __float22half2_rn(make_float2(v1.z, v1.w));
    *(float4*)&W16[row * F_IN + col] = u.f;
}

// ---------------------------------------------------------------------------
// Kernel 1 (MFMA, barrier-free): t[n][f] = sum_i x[n][i]*W[f][i].
// A frags: direct global fp32 load + cvt (no LDS). B frags: direct from W16
// (32 KB -> L1-resident, same addresses across all waves = broadcast hits).
// LDS: only a wave-private 4 KB t-staging bounce (scalar swizzled writes ->
// coalesced float4 reads). Zero __syncthreads in the whole kernel.
// C/D mapping (m89-verified): col = lane&15, row = (lane>>4)*4 + reg.
// ---------------------------------------------------------------------------
__global__ __launch_bounds__(256) void k1_proj(
    const float* __restrict__ x,     // [NN][128]
    const __half* __restrict__ W16,  // [128][128] fp16
    const float* __restrict__ As,    // [4][64]
    __half* __restrict__ t,          // [NN][128] fp16
    float* __restrict__ ssrc,        // [NN][4]
    float* __restrict__ sdst) {      // [NN][4]
    __shared__ __half tsh[4][16 * 128];  // 16 KB, wave-private regions

    const int tid = threadIdx.x;
    const int lane = tid & 63;
    const int wv = tid >> 6;
    const int base = blockIdx.x * 64;
    const int mb = wv * 16;    // wave's local node base
    const int lr = lane & 15;  // A-row (node) / B-row (feat) within tile
    const int lg = lane >> 4;  // k-group

    // --- A fragments: lane reads its own 32B fp32 slice per k-step, cvt ---
    int ng = base + mb + lr;
    if (ng >= NN) ng = NN - 1;  // clamp loads; stores guarded below
    const float* xrow = x + (long)ng * F_IN;

    f16x8 afr[4];
#pragma unroll
    for (int kk = 0; kk < 4; ++kk) {
        const float4 v0 = *(const float4*)(xrow + kk * 32 + lg * 8);
        const float4 v1 = *(const float4*)(xrow + kk * 32 + lg * 8 + 4);
        union { __half2 h2[4]; f16x8 f; } u;
        u.h2[0] = __float22half2_rn(make_float2(v0.x, v0.y));
        u.h2[1] = __float22half2_rn(make_float2(v0.z, v0.w));
        u.h2[2] = __float22half2_rn(make_float2(v1.x, v1.y));
        u.h2[3] = __float22half2_rn(make_float2(v1.z, v1.w));
        afr[kk] = u.f;
    }

    // --- 8 n-tiles of 16 feats; B frags straight from W16 (L1-hot) ---
    f32x4 acc[8];
#pragma unroll
    for (int nt = 0; nt < 8; ++nt) {
        f32x4 c = {0.f, 0.f, 0.f, 0.f};
#pragma unroll
        for (int kk = 0; kk < 4; ++kk) {
            const f16x8 b =
                *(const f16x8*)&W16[(nt * 16 + lr) * F_IN + kk * 32 + lg * 8];
            c = __builtin_amdgcn_mfma_f32_16x16x32_f16(afr[kk], b, c, 0, 0, 0);
        }
        acc[nt] = c;
    }

    // --- t store via wave-private LDS bounce (no barrier needed):
    //     scalar swizzled writes, then coalesced float4 reads/stores. ---
    __half* tst = tsh[wv];
#pragma unroll
    for (int nt = 0; nt < 8; ++nt) {
#pragma unroll
        for (int r = 0; r < 4; ++r) {
            const int node = lg * 4 + r;           // C/D row (verified m89)
            const int feat = nt * 16 + lr;         // C/D col
            tst[node * 128 + (feat ^ ((node & 7) << 3))] =
                __float2half_rn(acc[nt][r]);
        }
    }
#pragma unroll
    for (int r = 0; r < 4; ++r) {
        const int row = r * 4 + lg;
        const int n = base + mb + row;
        if (n < NN) {
            const float4 v =
                *(const float4*)&tst[row * 128 + ((lr * 8) ^ ((row & 7) << 3))];
            *(float4*)(t + (long)n * FTOT + lr * 8) = v;
        }
    }

    // --- ssrc/sdst from f32 acc: head h = n-tiles {2h, 2h+1};
    //     reduce over lr (16-lane groups) ---
#pragma unroll
    for (int h = 0; h < NH; ++h) {
        const float as0 = As[h * 64 + lr];
        const float as1 = As[h * 64 + 16 + lr];
        const float ad0 = As[h * 64 + 32 + lr];
        const float ad1 = As[h * 64 + 48 + lr];
#pragma unroll
        for (int r = 0; r < 4; ++r) {
            float ps = acc[2 * h][r] * as0 + acc[2 * h + 1][r] * as1;
            float pd = acc[2 * h][r] * ad0 + acc[2 * h + 1][r] * ad1;
            ps += __shfl_xor(ps, 1); ps += __shfl_xor(ps, 2);
            ps += __shfl_xor(ps, 4); ps += __shfl_xor(ps, 8);
            pd += __shfl_xor(pd, 1); pd += __shfl_xor(pd, 2);
            pd += __shfl_xor(pd, 4); pd += __shfl_xor(pd, 8);
            if (lr == 0) {
                const int n = base + mb + lg * 4 + r;
                if (n < NN) {
                    ssrc[(long)n * NH + h] = ps;
                    sdst[(long)n * NH + h] = pd;
                }
            }
        }
    }
}

// ---------------------------------------------------------------------------
// Kernel 2: FROZEN from round 10/11 (control for attribution).
// ---------------------------------------------------------------------------
__global__ __launch_bounds__(256) void k2_attn(
    const int* __restrict__ nidx,    // [NN][16]
    const __half* __restrict__ t,    // [NN][128] fp16
    const float* __restrict__ ssrc,  // [NN][4]
    const float* __restrict__ sdst,  // [NN][4]
    float* __restrict__ out) {       // [NN][128]
    __shared__ float salpha[4][17][4];  // [wave][edge][head]
    __shared__ int sidx[4][17];

    const int lane = threadIdx.x & 63;
    const int wv = threadIdx.x >> 6;
    const int n = blockIdx.x * 4 + wv;  // 25000 blocks x 4 waves = 100000

    // --- phase A: stage edge indices (lanes 0..16) ---
    if (lane < 17) {
        sidx[wv][lane] =
            (lane == 0)
                ? n
                : __builtin_nontemporal_load(&nidx[(long)n * DEG + (lane - 1)]);
    }
    __syncthreads();

    // --- phase B: prefetch all 17 feature rows (4B/lane; wave covers the
    //     full 256B fp16 row per edge in one coalesced load) ---
    unsigned int pre[17];
#pragma unroll
    for (int d = 0; d < 17; ++d) {
        pre[d] = *(const unsigned int*)(t + (long)sidx[wv][d] * FTOT + 2 * lane);
    }

    // --- score phase: lane = h*16 + j -> e[h][j]; j==15 also does edge 16 ---
    const int h = lane >> 4;
    const int j = lane & 15;
    const float ssv = ssrc[(long)n * NH + h];

    float e_a;
    {
        float c = ssv + sdst[(long)sidx[wv][j] * NH + h];
        c = fmaxf(c, 0.f) + 0.2f * fminf(c, 0.f);
        e_a = expf(c);
    }
    float e_b = -INFINITY;
    if (j == 15) {
        float c = ssv + sdst[(long)sidx[wv][16] * NH + h];
        c = fmaxf(c, 0.f) + 0.2f * fminf(c, 0.f);
        e_b = expf(c);
    }

    // --- softmax over 17 e-values, all 4 heads concurrently (16-lane groups) ---
    float m = fmaxf(e_a, e_b);
#pragma unroll
    for (int mask = 8; mask >= 1; mask >>= 1)
        m = fmaxf(m, __shfl_xor(m, mask));

    const float pa = expf(e_a - m);
    const float pb = (j == 15) ? expf(e_b - m) : 0.f;
    float s = pa + pb;
#pragma unroll
    for (int mask = 8; mask >= 1; mask >>= 1)
        s += __shfl_xor(s, mask);

    const float inv = 1.0f / s;
    salpha[wv][j][h] = pa * inv;
    if (j == 15) salpha[wv][16][h] = pb * inv;
    __syncthreads();

    // --- phase C: weighted sum over prefetched rows ---
    const int hc = lane >> 4;  // lane owns feats {2*lane, 2*lane+1}
    float ax = 0.f, ay = 0.f;
#pragma unroll
    for (int d = 0; d < 17; ++d) {
        const float a = salpha[wv][d][hc];
        const float2 f = __half22float2(*(const __half2*)&pre[d]);
        ax += a * f.x;
        ay += a * f.y;
    }

    // --- ELU + nontemporal store (out is write-once: keep it out of L2) ---
    const float yx = ax > 0.f ? ax : expm1f(ax);
    const float yy = ay > 0.f ? ay : expm1f(ay);
    union { float2 f2; double d; } o;
    o.f2 = make_float2(yx, yy);
    __builtin_nontemporal_store(o.d, (double*)(out + (long)n * FTOT + 2 * lane));
}

extern "C" void kernel_launch(void* const* d_in, const int* in_sizes, int n_in,
                              void* d_out, int out_size, void* d_ws, size_t ws_size,
                              hipStream_t stream) {
    const float* x = (const float*)d_in[0];
    const int* nidx = (const int*)d_in[1];
    const float* W = (const float*)d_in[2];   // Ws flattened: [h*32+o][i]
    const float* As = (const float*)d_in[3];  // [h][64]
    float* out = (float*)d_out;

    __half* t = (__half*)d_ws;                              // [NN][128] fp16
    float* ssrc = (float*)((char*)d_ws + (size_t)NN * FTOT * sizeof(__half));
    float* sdst = ssrc + (size_t)NN * NH;
    __half* W16 = (__half*)(sdst + (size_t)NN * NH);        // [128][128] fp16

    k0_wprep<<<8, 256, 0, stream>>>(W, W16);
    k1_proj<<<(NN + 63) / 64, 256, 0, stream>>>(x, W16, As, t, ssrc, sdst);
    k2_attn<<<NN / 4, 256, 0, stream>>>(nidx, t, ssrc, sdst, out);
}